// Round 5
// baseline (7902.677 us; speedup 1.0000x reference)
//
#include <hip/hip_runtime.h>
#include <hip/hip_fp16.h>
#include <cstdint>
#include <cstddef>

#define L_SEQ 2046      // subsampled sequence length
#define NBATCH 32
#define HID 256
#define M_PAD 65536     // padded row count (l2*32+n), 65472 real rows

typedef _Float16 h2vec  __attribute__((ext_vector_type(2)));
typedef _Float16 half8v __attribute__((ext_vector_type(8)));
typedef float    f32x4  __attribute__((ext_vector_type(4)));
typedef unsigned short u16x4 __attribute__((ext_vector_type(4)));

static __device__ __forceinline__ uint32_t pack2(float a, float b) {
  __half2 h = __floats2half2_rn(a, b);
  return __builtin_bit_cast(uint32_t, h);
}

static __device__ __forceinline__ float u16f(unsigned short u) {
  return __half2float(__builtin_bit_cast(__half, u));
}

static __device__ __forceinline__ void gload_lds16(const void* g, void* l) {
  __builtin_amdgcn_global_load_lds(
      (const __attribute__((address_space(1))) void*)g,
      (__attribute__((address_space(3))) void*)l, 16, 0, 0);
}

// ---- fused conv1 + im2col(for conv2 at even positions), output f16 ----
__global__ void k_conv_im2col(const float* __restrict__ X,
                              const float* __restrict__ W1,
                              const float* __restrict__ b1,
                              __half* __restrict__ A1h) {
  int j   = threadIdx.x;     // 0..383
  int row = blockIdx.x;      // 0..65535
  int l2 = row >> 5, n = row & 31;
  float v = 0.f;
  if (l2 < L_SEQ) {
    int ci = j / 3;
    int k  = j - 3 * ci;
    int p  = 2 * l2 + k;
    const float* xb = X + (size_t)n * 13 * 4096 + p;
    const float* w  = W1 + ci * 39;
    float acc = b1[ci];
#pragma unroll
    for (int c = 0; c < 13; c++) {
      const float* xp = xb + (size_t)c * 4096;
      acc += xp[0] * w[3*c+0] + xp[1] * w[3*c+1] + xp[2] * w[3*c+2];
    }
    v = acc;
  }
  A1h[(size_t)row * 384 + j] = __float2half(v);
}

// ---- f32 -> f16 elementwise (weight pre-convert) ----
__global__ void k_cvt_h(const float* __restrict__ src, __half* __restrict__ dst,
                        int nelem) {
  int i = blockIdx.x * 256 + threadIdx.x;
  if (i < nelem) dst[i] = __float2half(src[i]);
}

// ---- combined bias: biasD[i] = bih[i] + (i<512 ? bhh[i] : 0)  (r,z folded) ----
__global__ void k_biascomb(const float* __restrict__ bih_f,
                           const float* __restrict__ bhh_f,
                           const float* __restrict__ bih_b,
                           const float* __restrict__ bhh_b,
                           float* __restrict__ outFb, float* __restrict__ outBb) {
  int i = blockIdx.x * 256 + threadIdx.x;
  if (i < 768) {
    float af = i < 512 ? bhh_f[i] : 0.f;
    float ab = i < 512 ? bhh_b[i] : 0.f;
    outFb[i] = bih_f[i] + af;
    outBb[i] = bih_b[i] + ab;
  }
}

// ---- MFMA GEMM: C_f16[M][ldC](+col_off) = A_f16[M][K] @ B_f16[N][K]^T + bias
__global__ __launch_bounds__(256, 3) void k_gemm_mfma(
    const __half* __restrict__ A, const __half* __restrict__ Bh,
    const float* __restrict__ bias, __half* __restrict__ C,
    int K, int ldC, int col_off) {
  __shared__ __half Asl[128 * 64];   // 16 KiB
  __shared__ __half Bsl[128 * 64];   // 16 KiB
  const int tid  = threadIdx.x;
  const int wave = tid >> 6, lane = tid & 63;
  const int m_blk = blockIdx.x * 128;
  const int n_blk = blockIdx.y * 128;
  const int wm = wave >> 1, wn = wave & 1;

  f32x4 acc[4][4];
#pragma unroll
  for (int i = 0; i < 4; i++)
#pragma unroll
    for (int j = 0; j < 4; j++) acc[i][j] = (f32x4)0.f;

  int srow[4], sko[4];
#pragma unroll
  for (int i = 0; i < 4; i++) {
    int s = (i * 4 + wave) * 64 + lane;
    srow[i] = s >> 3;
    sko[i]  = (s & 7) ^ ((s >> 3) & 7);
  }

  for (int kc = 0; kc < K; kc += 64) {
#pragma unroll
    for (int i = 0; i < 4; i++) {
      int s = (i * 4 + wave) * 64 + lane;
      gload_lds16(A + (size_t)(m_blk + srow[i]) * K + kc + sko[i] * 8,
                  &Asl[s * 8]);
    }
#pragma unroll
    for (int i = 0; i < 4; i++) {
      int s = (i * 4 + wave) * 64 + lane;
      gload_lds16(Bh + (size_t)(n_blk + srow[i]) * K + kc + sko[i] * 8,
                  &Bsl[s * 8]);
    }
    __syncthreads();   // compiler drains vmcnt(0) before s_barrier
#pragma unroll
    for (int kb = 0; kb < 2; kb++) {
      half8v af[4], bf[4];
#pragma unroll
      for (int mi = 0; mi < 4; mi++) {
        int row = wm * 64 + mi * 16 + (lane & 15);
        int c   = (kb * 4 + (lane >> 4)) ^ (row & 7);
        af[mi] = *(const half8v*)&Asl[row * 64 + c * 8];
      }
#pragma unroll
      for (int ni = 0; ni < 4; ni++) {
        int row = wn * 64 + ni * 16 + (lane & 15);
        int c   = (kb * 4 + (lane >> 4)) ^ (row & 7);
        bf[ni] = *(const half8v*)&Bsl[row * 64 + c * 8];
      }
#pragma unroll
      for (int mi = 0; mi < 4; mi++)
#pragma unroll
        for (int ni = 0; ni < 4; ni++)
          acc[mi][ni] = __builtin_amdgcn_mfma_f32_16x16x32_f16(
              af[mi], bf[ni], acc[mi][ni], 0, 0, 0);
    }
    __syncthreads();
  }
#pragma unroll
  for (int ni = 0; ni < 4; ni++) {
    int col = wn * 64 + ni * 16 + (lane & 15);
    float bj = bias[n_blk + col];
#pragma unroll
    for (int mi = 0; mi < 4; mi++) {
      int row0 = m_blk + wm * 64 + mi * 16 + (lane >> 4) * 4;
#pragma unroll
      for (int r = 0; r < 4; r++) {
        C[(size_t)(row0 + r) * ldC + col_off + n_blk + col] =
            __float2half(acc[mi][ni][r] + bj);
      }
    }
  }
}

// ---- pre-pack Whh into per-(dir,wave,frag,lane) MFMA A-fragments ----
// Consumer: wave w (0..7), lane l.  Frag f = t6*8 + ks, t6 = gate*2 + jj.
// A-frag holds Whh[gate*256 + w*32 + jj*16 + (l&15)][ks*32 + (l>>4)*8 .. +8).
// Linear uint4 index: ((d*8 + w)*48 + f)*64 + l.
__global__ void k_packw3(const float* __restrict__ Whh_f,
                         const float* __restrict__ Whh_b,
                         uint4* __restrict__ Wpk) {
  int idx = blockIdx.x * 256 + threadIdx.x;   // 0..49151
  int d   = idx / 24576;
  int r   = idx - d * 24576;
  int w   = r / 3072;
  int r2  = r - w * 3072;
  int f   = r2 >> 6;
  int l   = r2 & 63;
  int t6  = f >> 3, ks = f & 7;
  int gate = t6 >> 1, jj = t6 & 1;
  int row = gate * 256 + w * 32 + jj * 16 + (l & 15);
  int k0  = ks * 32 + (l >> 4) * 8;
  const float* W = d ? Whh_b : Whh_f;
  const float* src = W + (size_t)row * 256 + k0;
  uint4 o;
  o.x = pack2(src[0], src[1]);
  o.y = pack2(src[2], src[3]);
  o.z = pack2(src[4], src[5]);
  o.w = pack2(src[6], src[7]);
  Wpk[(size_t)idx] = o;
}

// ---- GRU recurrence v10: MFMA matvec, batch-as-N ----
// 8 blocks = dir(2) x batch-octant(4); 512 threads (8 waves, 2/SIMD).
// Whh register-resident as 48 A-frags/lane (192 regs, AGPR-eligible since
// gfx950 MFMA reads A from AGPR).  Per step: gh[768x16] = Whh @ h_T via
// 48 MFMA/wave (6 M-tiles forming complete r/z/n triplets, N=1 tile,
// batches = B-cols, cols 8-15 zero).  Activation fully in-register (C/D
// layout col=lane&15=n, row=(lane>>4)*4+vv).  h in XOR-swizzled LDS
// [16][256] f16 double-buffered; gi prefetched via global_load_lds into
// per-wave LDS rows.  r/z bhh pre-folded into gih bias; only bhh_n here.
// One barrier/step.
__global__ __attribute__((amdgpu_flat_work_group_size(512, 512),
                          amdgpu_waves_per_eu(2, 2)))
void k_gru(
    const __half* __restrict__ gih, const uint4* __restrict__ Wpk,
    const float* __restrict__ bhh_f, const float* __restrict__ bhh_b,
    float* __restrict__ outF, __half* __restrict__ outBh,
    float* __restrict__ hT) {
  const int blk = blockIdx.x;       // 0..7
  const int dir = blk >> 2;         // 0 fwd, 1 bwd
  const int n0  = (blk & 3) * 8;    // batch octant base
  const int tid = threadIdx.x;
  const int w   = tid >> 6;         // wave 0..7
  const int l   = tid & 63;
  const int n   = l & 15;           // B-column (batch within tile)
  const int ng  = n & 7;
  const int hi  = l >> 4;           // 0..3
  const bool nvalid = (n < 8);

  // ---- load the 48 A-frags (stay live across whole loop; AGPR-eligible)
  uint4 wv[48];
  {
    const uint4* wp = Wpk + ((size_t)(dir * 8 + w) * 48) * 64 + l;
#pragma unroll
    for (int f = 0; f < 48; f++) wv[f] = wp[f * 64];
  }

  // bhh_n for my 8 g's: g = w*32 + jj*16 + hi*4 + vv
  const float* bhh = dir ? bhh_b : bhh_f;
  f32x4 bh2[2];
  bh2[0] = *(const f32x4*)&bhh[512 + w * 32 + 0 * 16 + hi * 4];
  bh2[1] = *(const f32x4*)&bhh[512 + w * 32 + 1 * 16 + hi * 4];

  __shared__ __align__(16) __half h_lds[2][16 * 256];  // 16 KiB
  __shared__ __align__(16) __half gi_lds[2][8 * 776];  // ~24 KiB
  {
    uint32_t* p = (uint32_t*)h_lds;
#pragma unroll
    for (int i = 0; i < 8; i++) p[i * 512 + tid] = 0u;  // zero both h buffers
  }
  float hp[2][4];
#pragma unroll
  for (int jj = 0; jj < 2; jj++)
#pragma unroll
    for (int vv = 0; vv < 4; vv++) hp[jj][vv] = 0.f;

  // gi staging: wave w stages batch (n0+w)'s 1536B dir-half row.
  const size_t gi_rowstep = (size_t)NBATCH * 1536;
#define STAGE_GI(tt, buf) do {                                              \
    int lidx_ = dir ? (L_SEQ - 1 - (tt)) : (tt);                            \
    const char* src_ = (const char*)(gih +                                   \
        ((size_t)lidx_ * NBATCH + n0 + w) * 1536 + dir * 768);              \
    char* dst_ = (char*)&gi_lds[buf][w * 776];                              \
    gload_lds16(src_ + l * 16, dst_ + l * 16);                              \
    if (l < 32) gload_lds16(src_ + 1024 + l * 16, dst_ + 1024 + l * 16);    \
  } while (0)

  STAGE_GI(0, 0);
  __syncthreads();

  int cur = 0;
  for (int t = 0; t < L_SEQ; t++) {
    if (t + 1 < L_SEQ) STAGE_GI(t + 1, cur ^ 1);

    // ---- MFMA phase: gh = Whh @ h_T
    f32x4 acc[6];
#pragma unroll
    for (int i = 0; i < 6; i++) acc[i] = (f32x4)0.f;
    {
      const __half* hb = h_lds[cur];
#pragma unroll
      for (int ks = 0; ks < 8; ks++) {
        int c_lin = ks * 4 + hi;
        int c_swz = (c_lin & 24) | ((c_lin & 7) ^ ng);
        half8v bf = *(const half8v*)&hb[n * 256 + c_swz * 8];
#pragma unroll
        for (int t6 = 0; t6 < 6; t6++)
          acc[t6] = __builtin_amdgcn_mfma_f32_16x16x32_f16(
              __builtin_bit_cast(half8v, wv[t6 * 8 + ks]), bf, acc[t6], 0, 0, 0);
      }
    }

    // ---- activation phase (in-register; lanes n>=8 compute junk, masked)
    const int lidx = dir ? (L_SEQ - 1 - t) : t;
    const __half* gi = &gi_lds[cur][ng * 776];
    u16x4 giv[3][2];
#pragma unroll
    for (int gt = 0; gt < 3; gt++)
#pragma unroll
      for (int jj = 0; jj < 2; jj++)
        giv[gt][jj] = *(const u16x4*)&gi[gt * 256 + w * 32 + jj * 16 + hi * 4];

#pragma unroll
    for (int jj = 0; jj < 2; jj++) {
      float hnew[4];
#pragma unroll
      for (int vv = 0; vv < 4; vv++) {
        float hr = acc[0 + jj][vv];              // r-gate (bias folded in gih)
        float hz = acc[2 + jj][vv];              // z-gate
        float hn = acc[4 + jj][vv] + bh2[jj][vv];// n-gate + bhh_n
        float ir  = u16f(giv[0][jj][vv]);
        float iz  = u16f(giv[1][jj][vv]);
        float inn = u16f(giv[2][jj][vv]);
        float rr = 1.f / (1.f + __expf(-(ir + hr)));
        float zz = 1.f / (1.f + __expf(-(iz + hz)));
        float e  = __expf(2.f * (inn + rr * hn));
        float nn = 1.f - 2.f / (e + 1.f);        // tanh, safe at +/-inf
        hnew[vv] = (1.f - zz) * nn + zz * hp[jj][vv];
        hp[jj][vv] = hnew[vv];
      }
      if (nvalid) {
        const int gbase = w * 32 + jj * 16 + hi * 4;
        uint2 pk;
        pk.x = pack2(hnew[0], hnew[1]);
        pk.y = pack2(hnew[2], hnew[3]);
        // swizzled h write (same per-row XOR as the B-frag read)
        int c_lin = gbase >> 3;
        int c_swz = (c_lin & 24) | ((c_lin & 7) ^ ng);
        *(uint2*)&h_lds[cur ^ 1][n * 256 + c_swz * 8 + (gbase & 7)] = pk;
        const size_t oi = ((size_t)lidx * NBATCH + n0 + n) * HID + gbase;
        if (dir == 0) {
          f32x4 o; o[0] = hnew[0]; o[1] = hnew[1]; o[2] = hnew[2]; o[3] = hnew[3];
          *(f32x4*)&outF[oi] = o;
        } else {
          *(uint2*)&outBh[oi] = pk;
        }
      }
    }
    __syncthreads();
    cur ^= 1;
  }

  if (dir == 1 && nvalid) {
#pragma unroll
    for (int jj = 0; jj < 2; jj++) {
      const int gbase = w * 32 + jj * 16 + hi * 4;
      f32x4 o; o[0] = hp[jj][0]; o[1] = hp[jj][1]; o[2] = hp[jj][2]; o[3] = hp[jj][3];
      *(f32x4*)&hT[(size_t)(n0 + n) * HID + gbase] = o;
    }
  }
#undef STAGE_GI
}

// ---- combine (in place over outF/d_out): relu(0.5*(out_f + out_b[...,::-1]))
__global__ void k_combine(float* __restrict__ outF,
                          const __half* __restrict__ outBh) {
  int idx = blockIdx.x * 256 + threadIdx.x;
  int c = idx & 255;
  float v = 0.5f * (outF[idx] + __half2float(outBh[idx + 255 - 2 * c]));
  outF[idx] = v > 0.f ? v : 0.f;
}

extern "C" void kernel_launch(void* const* d_in, const int* in_sizes, int n_in,
                              void* d_out, int out_size, void* d_ws, size_t ws_size,
                              hipStream_t stream) {
  const float* X     = (const float*)d_in[0];
  const float* W1    = (const float*)d_in[1];
  const float* b1    = (const float*)d_in[2];
  const float* W2    = (const float*)d_in[3];
  const float* b2    = (const float*)d_in[4];
  const float* Wih_f = (const float*)d_in[5];
  const float* Whh_f = (const float*)d_in[6];
  const float* bih_f = (const float*)d_in[7];
  const float* bhh_f = (const float*)d_in[8];
  const float* Wih_b = (const float*)d_in[9];
  const float* Whh_b = (const float*)d_in[10];
  const float* bih_b = (const float*)d_in[11];
  const float* bhh_b = (const float*)d_in[12];

  // Workspace (bytes), max footprint 251,658,240:
  //   gih   : [0, 201326592)           65536 x 1536 halves (written by gemm2/3)
  //   W2h   : [0, 196608)              alias in gih region; live only for gemm1
  //   A1h   : [201326592, 251658240)   65536 x 384 halves; DEAD after gemm1
  //   outBh : [201326592, 234848256)   alias (written by k_gru)
  //   Wpk3  : [234848768, 235635200)   MFMA A-frag stream, written AFTER gemm1
  //   WihfH : [235635200, 236028416)   768x256 f16
  //   WihbH : [236028416, 236421632)   768x256 f16
  //   biasF : [236421632, 236424704)   768 f32 (bih_f + folded bhh_f r/z)
  //   biasB : [236424704, 236427776)   768 f32
  char* wsb = (char*)d_ws;
  __half* gih   = (__half*)(wsb);
  __half* W2h   = (__half*)(wsb);
  __half* A1h   = (__half*)(wsb + 201326592);
  __half* outBh = (__half*)(wsb + 201326592);
  uint4*  Wpk3  = (uint4*)(wsb + 234848768);
  __half* WihfH = (__half*)(wsb + 235635200);
  __half* WihbH = (__half*)(wsb + 236028416);
  float*  biasF = (float*)(wsb + 236421632);
  float*  biasB = (float*)(wsb + 236424704);

  float*  outF  = (float*)d_out;
  __half* xsubh = (__half*)d_out;                      // scratch in d_out
  float*  hT    = outF + (size_t)L_SEQ * NBATCH * HID;

  k_conv_im2col<<<dim3(M_PAD), 384, 0, stream>>>(X, W1, b1, A1h);
  k_cvt_h<<<dim3(384), 256, 0, stream>>>(W2, W2h, 98304);
  k_gemm_mfma<<<dim3(512, 2), 256, 0, stream>>>(A1h, W2h, b2, xsubh, 384, 256, 0);
  // A1h dead; Wpk3/WihH/bias regions free now
  k_cvt_h<<<dim3(768), 256, 0, stream>>>(Wih_f, WihfH, 196608);
  k_cvt_h<<<dim3(768), 256, 0, stream>>>(Wih_b, WihbH, 196608);
  k_packw3<<<dim3(192), 256, 0, stream>>>(Whh_f, Whh_b, Wpk3);
  k_biascomb<<<dim3(3), 256, 0, stream>>>(bih_f, bhh_f, bih_b, bhh_b, biasF, biasB);
  k_gemm_mfma<<<dim3(512, 6), 256, 0, stream>>>(xsubh, WihfH, biasF, gih, 256, 1536, 0);
  k_gemm_mfma<<<dim3(512, 6), 256, 0, stream>>>(xsubh, WihbH, biasB, gih, 256, 1536, 768);
  k_gru<<<dim3(8), 512, 0, stream>>>(gih, Wpk3, bhh_f, bhh_b, outF, outBh, hT);
  k_combine<<<dim3(65472), 256, 0, stream>>>(outF, outBh);
}

// Round 6
// 4403.502 us; speedup vs baseline: 1.7946x; 1.7946x over previous
//
#include <hip/hip_runtime.h>
#include <hip/hip_fp16.h>
#include <cstdint>
#include <cstddef>

#define L_SEQ 2046      // subsampled sequence length
#define NBATCH 32
#define HID 256
#define M_PAD 65536     // padded row count (l2*32+n), 65472 real rows

typedef _Float16 h2vec  __attribute__((ext_vector_type(2)));
typedef _Float16 half8v __attribute__((ext_vector_type(8)));
typedef float    f32x4  __attribute__((ext_vector_type(4)));
typedef unsigned short u16x4 __attribute__((ext_vector_type(4)));

static __device__ __forceinline__ uint32_t pack2(float a, float b) {
  __half2 h = __floats2half2_rn(a, b);
  return __builtin_bit_cast(uint32_t, h);
}

static __device__ __forceinline__ float u16f(unsigned short u) {
  return __half2float(__builtin_bit_cast(__half, u));
}

static __device__ __forceinline__ float fdot2u(uint32_t w, uint32_t h, float c) {
#if __has_builtin(__builtin_amdgcn_fdot2)
  return __builtin_amdgcn_fdot2(__builtin_bit_cast(h2vec, w),
                                __builtin_bit_cast(h2vec, h), c, false);
#else
  __half2 a = __builtin_bit_cast(__half2, w);
  __half2 b = __builtin_bit_cast(__half2, h);
  float2 fa = __half22float2(a), fb = __half22float2(b);
  return c + fa.x * fb.x + fa.y * fb.y;
#endif
}

static __device__ __forceinline__ void gload_lds16(const void* g, void* l) {
  __builtin_amdgcn_global_load_lds(
      (const __attribute__((address_space(1))) void*)g,
      (__attribute__((address_space(3))) void*)l, 16, 0, 0);
}

// ---- fused conv1 + im2col(for conv2 at even positions), output f16 ----
__global__ void k_conv_im2col(const float* __restrict__ X,
                              const float* __restrict__ W1,
                              const float* __restrict__ b1,
                              __half* __restrict__ A1h) {
  int j   = threadIdx.x;     // 0..383
  int row = blockIdx.x;      // 0..65535
  int l2 = row >> 5, n = row & 31;
  float v = 0.f;
  if (l2 < L_SEQ) {
    int ci = j / 3;
    int k  = j - 3 * ci;
    int p  = 2 * l2 + k;
    const float* xb = X + (size_t)n * 13 * 4096 + p;
    const float* w  = W1 + ci * 39;
    float acc = b1[ci];
#pragma unroll
    for (int c = 0; c < 13; c++) {
      const float* xp = xb + (size_t)c * 4096;
      acc += xp[0] * w[3*c+0] + xp[1] * w[3*c+1] + xp[2] * w[3*c+2];
    }
    v = acc;
  }
  A1h[(size_t)row * 384 + j] = __float2half(v);
}

// ---- f32 -> f16 elementwise (weight pre-convert) ----
__global__ void k_cvt_h(const float* __restrict__ src, __half* __restrict__ dst,
                        int nelem) {
  int i = blockIdx.x * 256 + threadIdx.x;
  if (i < nelem) dst[i] = __float2half(src[i]);
}

// ---- combined bias: biasD[i] = bih[i] + (i<512 ? bhh[i] : 0)  (r,z folded) ----
__global__ void k_biascomb(const float* __restrict__ bih_f,
                           const float* __restrict__ bhh_f,
                           const float* __restrict__ bih_b,
                           const float* __restrict__ bhh_b,
                           float* __restrict__ outFb, float* __restrict__ outBb) {
  int i = blockIdx.x * 256 + threadIdx.x;
  if (i < 768) {
    float af = i < 512 ? bhh_f[i] : 0.f;
    float ab = i < 512 ? bhh_b[i] : 0.f;
    outFb[i] = bih_f[i] + af;
    outBb[i] = bih_b[i] + ab;
  }
}

// ---- MFMA GEMM: C_f16[M][ldC](+col_off) = A_f16[M][K] @ B_f16[N][K]^T + bias
__global__ __launch_bounds__(256, 3) void k_gemm_mfma(
    const __half* __restrict__ A, const __half* __restrict__ Bh,
    const float* __restrict__ bias, __half* __restrict__ C,
    int K, int ldC, int col_off) {
  __shared__ __half Asl[128 * 64];   // 16 KiB
  __shared__ __half Bsl[128 * 64];   // 16 KiB
  const int tid  = threadIdx.x;
  const int wave = tid >> 6, lane = tid & 63;
  const int m_blk = blockIdx.x * 128;
  const int n_blk = blockIdx.y * 128;
  const int wm = wave >> 1, wn = wave & 1;

  f32x4 acc[4][4];
#pragma unroll
  for (int i = 0; i < 4; i++)
#pragma unroll
    for (int j = 0; j < 4; j++) acc[i][j] = (f32x4)0.f;

  int srow[4], sko[4];
#pragma unroll
  for (int i = 0; i < 4; i++) {
    int s = (i * 4 + wave) * 64 + lane;
    srow[i] = s >> 3;
    sko[i]  = (s & 7) ^ ((s >> 3) & 7);
  }

  for (int kc = 0; kc < K; kc += 64) {
#pragma unroll
    for (int i = 0; i < 4; i++) {
      int s = (i * 4 + wave) * 64 + lane;
      gload_lds16(A + (size_t)(m_blk + srow[i]) * K + kc + sko[i] * 8,
                  &Asl[s * 8]);
    }
#pragma unroll
    for (int i = 0; i < 4; i++) {
      int s = (i * 4 + wave) * 64 + lane;
      gload_lds16(Bh + (size_t)(n_blk + srow[i]) * K + kc + sko[i] * 8,
                  &Bsl[s * 8]);
    }
    __syncthreads();   // compiler drains vmcnt(0) before s_barrier
#pragma unroll
    for (int kb = 0; kb < 2; kb++) {
      half8v af[4], bf[4];
#pragma unroll
      for (int mi = 0; mi < 4; mi++) {
        int row = wm * 64 + mi * 16 + (lane & 15);
        int c   = (kb * 4 + (lane >> 4)) ^ (row & 7);
        af[mi] = *(const half8v*)&Asl[row * 64 + c * 8];
      }
#pragma unroll
      for (int ni = 0; ni < 4; ni++) {
        int row = wn * 64 + ni * 16 + (lane & 15);
        int c   = (kb * 4 + (lane >> 4)) ^ (row & 7);
        bf[ni] = *(const half8v*)&Bsl[row * 64 + c * 8];
      }
#pragma unroll
      for (int mi = 0; mi < 4; mi++)
#pragma unroll
        for (int ni = 0; ni < 4; ni++)
          acc[mi][ni] = __builtin_amdgcn_mfma_f32_16x16x32_f16(
              af[mi], bf[ni], acc[mi][ni], 0, 0, 0);
    }
    __syncthreads();
  }
#pragma unroll
  for (int ni = 0; ni < 4; ni++) {
    int col = wn * 64 + ni * 16 + (lane & 15);
    float bj = bias[n_blk + col];
#pragma unroll
    for (int mi = 0; mi < 4; mi++) {
      int row0 = m_blk + wm * 64 + mi * 16 + (lane >> 4) * 4;
#pragma unroll
      for (int r = 0; r < 4; r++) {
        C[(size_t)(row0 + r) * ldC + col_off + n_blk + col] =
            __float2half(acc[mi][ni][r] + bj);
      }
    }
  }
}

// ---- pack Whh g-hi half for VALU waves: consumer (vw 0..3, lane) ----
// kh=lane&1, g=128+vw*32+(lane>>1); quad jq=q*3+gt holds
// Whh[gt*256+g][kh*128+8q..+8).  Addr: Wv[d*12288 + jq*256 + vw*64+lane].
__global__ void k_packw_v(const float* __restrict__ Whh_f,
                          const float* __restrict__ Whh_b,
                          uint4* __restrict__ Wv) {
  int idx = blockIdx.x * 256 + threadIdx.x;   // 0..24575
  int d    = idx / 12288;
  int r    = idx - d * 12288;
  int jq   = r >> 8;
  int cons = r & 255;
  int q  = jq / 3, gt = jq - 3 * q;
  int vw = cons >> 6, lane = cons & 63;
  int kh = lane & 1, g = 128 + vw * 32 + (lane >> 1);
  const float* W = d ? Whh_b : Whh_f;
  const float* src = W + (size_t)(gt * 256 + g) * 256 + kh * 128 + 8 * q;
  uint4 o;
  o.x = pack2(src[0], src[1]);
  o.y = pack2(src[2], src[3]);
  o.z = pack2(src[4], src[5]);
  o.w = pack2(src[6], src[7]);
  Wv[(size_t)idx] = o;
}

// ---- pack Whh g-lo half as MFMA A-frags for waves mw 0..3 ----
// Frag f = t6*8+ks, t6 = gate*2+j: holds
// Whh[gate*256 + mw*32 + j*16 + (l&15)][ks*32 + (l>>4)*8 .. +8).
// Addr: Wm[((d*4+mw)*48 + f)*64 + l].
__global__ void k_packw_m(const float* __restrict__ Whh_f,
                          const float* __restrict__ Whh_b,
                          uint4* __restrict__ Wm) {
  int idx = blockIdx.x * 256 + threadIdx.x;   // 0..24575
  int d  = idx / 12288;
  int r  = idx - d * 12288;
  int mw = r / 3072;
  int r2 = r - mw * 3072;
  int f  = r2 >> 6;
  int l  = r2 & 63;
  int t6 = f >> 3, ks = f & 7;
  int gate = t6 >> 1, j = t6 & 1;
  int row = gate * 256 + mw * 32 + j * 16 + (l & 15);
  int k0  = ks * 32 + (l >> 4) * 8;
  const float* W = d ? Whh_b : Whh_f;
  const float* src = W + (size_t)row * 256 + k0;
  uint4 o;
  o.x = pack2(src[0], src[1]);
  o.y = pack2(src[2], src[3]);
  o.z = pack2(src[4], src[5]);
  o.w = pack2(src[6], src[7]);
  Wm[(size_t)idx] = o;
}

// ---- GRU recurrence v11: hybrid MFMA+VALU wave specialization ----
// 64 blocks = (dir,n); 512 threads, 8 waves, 2/SIMD.  Waves 0-3: MFMA path,
// g in [0,128) (6 M-tiles x 8 K-frags register-resident; B = h broadcast to
// all 16 cols from plain LDS copy -> conflict-free).  Waves 4-7: v6 VALU
// dot2 path, g in [128,256) (one VALU wave per SIMD under i%4 mapping ->
// exclusive VALU pipe).  Matrix and vector pipes run concurrently (m114).
// h kept in TWO LDS copies (plain for MFMA-B, v6-swizzled for VALU),
// double-buffered; disjoint writer regions.  gi staged one step ahead by
// wave 0 via global_load_lds (barrier drain lands ~1 step after issue).
// One barrier/step.
__global__ __attribute__((amdgpu_flat_work_group_size(512, 512),
                          amdgpu_waves_per_eu(2, 2)))
void k_gru(
    const __half* __restrict__ gih,
    const uint4* __restrict__ Wv, const uint4* __restrict__ Wm,
    const float* __restrict__ bhh_f, const float* __restrict__ bhh_b,
    float* __restrict__ outF, __half* __restrict__ outBh,
    float* __restrict__ hT) {
  const int blk = blockIdx.x;
  const int dir = blk >> 5;    // 0 fwd, 1 bwd
  const int n   = blk & 31;
  const int tid = threadIdx.x;
  const int wave = tid >> 6;
  const int lane = tid & 63;
  const float* bhh = dir ? bhh_b : bhh_f;

  __shared__ __align__(16) __half h_pl[2][256];    // plain layout
  __shared__ __align__(16) __half h_sw[2][256];    // v6 granule-swizzled
  __shared__ __align__(16) __half gi_lds[2][768];  // staged gi row (one dir)

  if (tid < 128) {
    ((uint32_t*)h_pl)[tid] = 0u;   // zero h_pl[0]
    ((uint32_t*)h_sw)[tid] = 0u;   // zero h_sw[0]
  }

  const __half* gsrc0 = gih +
      ((size_t)(dir ? (size_t)(L_SEQ - 1) * NBATCH : 0) + n) * 1536 + dir * 768;
  const ptrdiff_t gstepB = (dir ? -(ptrdiff_t)(NBATCH * 1536)
                               :  (ptrdiff_t)(NBATCH * 1536)) * 2;

  if (wave < 4) {
    // ================= MFMA path: g in [0,128) =================
    const int mw  = wave;
    const int hi4 = lane >> 4;             // 0..3
    const bool al = (lane & 15) == 0;      // activation lanes

    uint4 wm[48];
    {
      const uint4* wp = Wm + ((size_t)(dir * 4 + mw) * 48) * 64 + lane;
#pragma unroll
      for (int f = 0; f < 48; f++) wm[f] = wp[f * 64];
    }
    f32x4 bhn[2];
    bhn[0] = *(const f32x4*)&bhh[512 + mw * 32 + 0 * 16 + hi4 * 4];
    bhn[1] = *(const f32x4*)&bhh[512 + mw * 32 + 1 * 16 + hi4 * 4];
    f32x4 hp[2];
    hp[0] = (f32x4)0.f; hp[1] = (f32x4)0.f;

    const char* gcur = (const char*)gsrc0;
    if (mw == 0) {   // stage gi(t=0)
      gload_lds16(gcur + lane * 16, (char*)&gi_lds[0][0] + lane * 16);
      if (lane < 32)
        gload_lds16(gcur + 1024 + lane * 16, (char*)&gi_lds[0][0] + 1024 + lane * 16);
    }
    gcur += gstepB;
    __syncthreads();

    int cur = 0;
    for (int t = 0; t < L_SEQ; t++) {
      if (mw == 0 && t + 1 < L_SEQ) {   // stage gi(t+1) into buf cur^1
        gload_lds16(gcur + lane * 16, (char*)&gi_lds[cur ^ 1][0] + lane * 16);
        if (lane < 32)
          gload_lds16(gcur + 1024 + lane * 16,
                      (char*)&gi_lds[cur ^ 1][0] + 1024 + lane * 16);
      }
      gcur += gstepB;

      f32x4 acc[6];
#pragma unroll
      for (int i = 0; i < 6; i++) acc[i] = (f32x4)0.f;
      {
        const __half* hb = h_pl[cur];
#pragma unroll
        for (int ks = 0; ks < 8; ks++) {
          half8v bf = *(const half8v*)&hb[ks * 32 + hi4 * 8];  // 16-lane bcast
#pragma unroll
          for (int t6 = 0; t6 < 6; t6++)
            acc[t6] = __builtin_amdgcn_mfma_f32_16x16x32_f16(
                __builtin_bit_cast(half8v, wm[t6 * 8 + ks]), bf, acc[t6], 0, 0, 0);
        }
      }

      if (al) {
        const int lidx = dir ? (L_SEQ - 1 - t) : t;
        const __half* gi = gi_lds[cur];
#pragma unroll
        for (int j = 0; j < 2; j++) {
          const int g0 = mw * 32 + j * 16 + hi4 * 4;
          u16x4 vr = *(const u16x4*)&gi[g0];
          u16x4 vz = *(const u16x4*)&gi[256 + g0];
          u16x4 vn = *(const u16x4*)&gi[512 + g0];
          float hnew[4];
#pragma unroll
          for (int rr = 0; rr < 4; rr++) {
            float hr = acc[j][rr];                 // r (bias folded in gih)
            float hz = acc[2 + j][rr];             // z
            float hn = acc[4 + j][rr] + bhn[j][rr];// n + bhh_n
            float ir  = u16f(vr[rr]);
            float iz  = u16f(vz[rr]);
            float inn = u16f(vn[rr]);
            float rv = 1.f / (1.f + __expf(-(ir + hr)));
            float zz = 1.f / (1.f + __expf(-(iz + hz)));
            float e  = __expf(2.f * (inn + rv * hn));
            float nn = 1.f - 2.f / (e + 1.f);      // tanh, safe at +/-inf
            hnew[rr] = (1.f - zz) * nn + zz * hp[j][rr];
            hp[j][rr] = hnew[rr];
          }
          uint2 pk;
          pk.x = pack2(hnew[0], hnew[1]);
          pk.y = pack2(hnew[2], hnew[3]);
          *(uint2*)&h_pl[cur ^ 1][g0] = pk;
          const int sli = ((g0 >> 3) * 2) * 8 + (g0 & 7);  // g0<128 -> kh bit 0
          *(uint2*)&h_sw[cur ^ 1][sli] = pk;
          const size_t oi = ((size_t)lidx * NBATCH + n) * HID + g0;
          if (dir == 0) {
            f32x4 o; o[0] = hnew[0]; o[1] = hnew[1]; o[2] = hnew[2]; o[3] = hnew[3];
            *(f32x4*)&outF[oi] = o;
          } else {
            *(uint2*)&outBh[oi] = pk;
          }
        }
      }
      __syncthreads();
      cur ^= 1;
    }
    if (dir == 1 && al) {
#pragma unroll
      for (int j = 0; j < 2; j++) {
        const int g0 = mw * 32 + j * 16 + hi4 * 4;
        f32x4 o; o[0] = hp[j][0]; o[1] = hp[j][1]; o[2] = hp[j][2]; o[3] = hp[j][3];
        *(f32x4*)&hT[(size_t)n * HID + g0] = o;
      }
    }
  } else {
    // ================= VALU path (v6 core): g in [128,256) =================
    const int vw = wave - 4;
    const int kh = lane & 1;
    const int g  = 128 + vw * 32 + (lane >> 1);

    uint4 wv[48];
    {
      const uint4* wp = Wv + (size_t)dir * 12288 + vw * 64 + lane;
#pragma unroll
      for (int jq = 0; jq < 48; jq++) wv[jq] = wp[jq * 256];
#pragma unroll
      for (int jq = 0; jq < 48; jq++) {
        asm volatile("" : "+v"(wv[jq].x), "+v"(wv[jq].y), "+v"(wv[jq].z), "+v"(wv[jq].w));
      }
    }
    const float bh2 = bhh[512 + g];
    float hp = 0.f;
    __syncthreads();

    int cur = 0;
    for (int t = 0; t < L_SEQ; t++) {
      const uint4* hb = (const uint4*)h_sw[cur];
      float a0 = 0.f, a1 = 0.f, a2 = 0.f;
#pragma unroll
      for (int q = 0; q < 16; q++) {
        uint4 hq = hb[q * 2 + kh];
        uint4 u0 = wv[q * 3 + 0];
        uint4 u1 = wv[q * 3 + 1];
        uint4 u2 = wv[q * 3 + 2];
        a0 = fdot2u(u0.x, hq.x, a0);
        a0 = fdot2u(u0.y, hq.y, a0);
        a0 = fdot2u(u0.z, hq.z, a0);
        a0 = fdot2u(u0.w, hq.w, a0);
        a1 = fdot2u(u1.x, hq.x, a1);
        a1 = fdot2u(u1.y, hq.y, a1);
        a1 = fdot2u(u1.z, hq.z, a1);
        a1 = fdot2u(u1.w, hq.w, a1);
        a2 = fdot2u(u2.x, hq.x, a2);
        a2 = fdot2u(u2.y, hq.y, a2);
        a2 = fdot2u(u2.z, hq.z, a2);
        a2 = fdot2u(u2.w, hq.w, a2);
      }
      a0 += __shfl_xor(a0, 1);
      a1 += __shfl_xor(a1, 1);
      a2 += __shfl_xor(a2, 1);

      if (kh == 0) {
        const __half* gi = gi_lds[cur];
        float ir  = __half2float(gi[g]);
        float iz  = __half2float(gi[256 + g]);
        float inn = __half2float(gi[512 + g]);
        float hr = a0;             // r/z bias folded into gih
        float hz = a1;
        float hn = a2 + bh2;
        float rv = 1.f / (1.f + __expf(-(ir + hr)));
        float zz = 1.f / (1.f + __expf(-(iz + hz)));
        float e  = __expf(2.f * (inn + rv * hn));
        float nn = 1.f - 2.f / (e + 1.f);
        float hnew = (1.f - zz) * nn + zz * hp;
        hp = hnew;
        __half hh = __float2half(hnew);
        const int swi = ((g & 127) >> 3) * 16 + (g >> 7) * 8 + (g & 7);
        h_sw[cur ^ 1][swi] = hh;
        h_pl[cur ^ 1][g]   = hh;
        const int lidx = dir ? (L_SEQ - 1 - t) : t;
        const uint32_t oi = ((uint32_t)lidx * NBATCH + n) * HID + g;
        if (dir == 0) outF[oi] = hnew;
        else          outBh[oi] = hh;
      }
      __syncthreads();
      cur ^= 1;
    }
    if (dir == 1 && kh == 0) hT[n * HID + g] = hp;
  }
}

// ---- combine (in place over outF/d_out): relu(0.5*(out_f + out_b[...,::-1]))
__global__ void k_combine(float* __restrict__ outF,
                          const __half* __restrict__ outBh) {
  int idx = blockIdx.x * 256 + threadIdx.x;
  int c = idx & 255;
  float v = 0.5f * (outF[idx] + __half2float(outBh[idx + 255 - 2 * c]));
  outF[idx] = v > 0.f ? v : 0.f;
}

extern "C" void kernel_launch(void* const* d_in, const int* in_sizes, int n_in,
                              void* d_out, int out_size, void* d_ws, size_t ws_size,
                              hipStream_t stream) {
  const float* X     = (const float*)d_in[0];
  const float* W1    = (const float*)d_in[1];
  const float* b1    = (const float*)d_in[2];
  const float* W2    = (const float*)d_in[3];
  const float* b2    = (const float*)d_in[4];
  const float* Wih_f = (const float*)d_in[5];
  const float* Whh_f = (const float*)d_in[6];
  const float* bih_f = (const float*)d_in[7];
  const float* bhh_f = (const float*)d_in[8];
  const float* Wih_b = (const float*)d_in[9];
  const float* Whh_b = (const float*)d_in[10];
  const float* bih_b = (const float*)d_in[11];
  const float* bhh_b = (const float*)d_in[12];

  // Workspace (bytes), max footprint 251,658,240:
  //   gih   : [0, 201326592)           65536 x 1536 halves (written by gemm2/3)
  //   W2h   : [0, 196608)              alias in gih region; live only for gemm1
  //   A1h   : [201326592, 251658240)   65536 x 384 halves; DEAD after gemm1
  //   outBh : [201326592, 234848256)   alias (written by k_gru)
  //   Wv    : [234848768, 235241984)   VALU-half pack, written AFTER gemm1
  //   Wm    : [235241984, 235635200)   MFMA A-frag pack, written AFTER gemm1
  //   WihfH : [235635200, 236028416)   768x256 f16
  //   WihbH : [236028416, 236421632)   768x256 f16
  //   biasF : [236421632, 236424704)   768 f32 (bih_f + folded bhh_f r/z)
  //   biasB : [236424704, 236427776)   768 f32
  char* wsb = (char*)d_ws;
  __half* gih   = (__half*)(wsb);
  __half* W2h   = (__half*)(wsb);
  __half* A1h   = (__half*)(wsb + 201326592);
  __half* outBh = (__half*)(wsb + 201326592);
  uint4*  Wv    = (uint4*)(wsb + 234848768);
  uint4*  Wm    = (uint4*)(wsb + 235241984);
  __half* WihfH = (__half*)(wsb + 235635200);
  __half* WihbH = (__half*)(wsb + 236028416);
  float*  biasF = (float*)(wsb + 236421632);
  float*  biasB = (float*)(wsb + 236424704);

  float*  outF  = (float*)d_out;
  __half* xsubh = (__half*)d_out;                      // scratch in d_out
  float*  hT    = outF + (size_t)L_SEQ * NBATCH * HID;

  k_conv_im2col<<<dim3(M_PAD), 384, 0, stream>>>(X, W1, b1, A1h);
  k_cvt_h<<<dim3(384), 256, 0, stream>>>(W2, W2h, 98304);
  k_gemm_mfma<<<dim3(512, 2), 256, 0, stream>>>(A1h, W2h, b2, xsubh, 384, 256, 0);
  // A1h dead; Wv/Wm/WihH/bias regions free now
  k_cvt_h<<<dim3(768), 256, 0, stream>>>(Wih_f, WihfH, 196608);
  k_cvt_h<<<dim3(768), 256, 0, stream>>>(Wih_b, WihbH, 196608);
  k_packw_v<<<dim3(96), 256, 0, stream>>>(Whh_f, Whh_b, Wv);
  k_packw_m<<<dim3(96), 256, 0, stream>>>(Whh_f, Whh_b, Wm);
  k_biascomb<<<dim3(3), 256, 0, stream>>>(bih_f, bhh_f, bih_b, bhh_b, biasF, biasB);
  k_gemm_mfma<<<dim3(512, 6), 256, 0, stream>>>(xsubh, WihfH, biasF, gih, 256, 1536, 0);
  k_gemm_mfma<<<dim3(512, 6), 256, 0, stream>>>(xsubh, WihbH, biasB, gih, 256, 1536, 768);
  k_gru<<<dim3(64), 512, 0, stream>>>(gih, Wv, Wm, bhh_f, bhh_b, outF, outBh, hT);
  k_combine<<<dim3(65472), 256, 0, stream>>>(outF, outBh);
}